// Round 11
// baseline (8816.558 us; speedup 1.0000x reference)
//
#include <hip/hip_runtime.h>
#include <hip/hip_bf16.h>

#define LN_EPS 1e-5f

// NAIVE KERNEL, formula exactly as displayed (shape-forced to be the executed
// semantics), dict input order, FP32 OUTPUT STORES (the one never-tested
// component: all prior rounds wrote packed bf16 ushorts).
// One wave per output row; no LDS, no barriers. Correctness round.
__global__ __launch_bounds__(256) void mpnn_naive(
    const float* __restrict__ inR, const float* __restrict__ inL,
    const float* __restrict__ W1, const float* __restrict__ b1,
    const float* __restrict__ W2, const float* __restrict__ b2,
    const float* __restrict__ gamma, const float* __restrict__ beta,
    float* __restrict__ out, int E)
{
    const int lane = threadIdx.x & 63;
    const int wib  = threadIdx.x >> 6;               // wave in block (0..3)
    const long nrows = 2L * E;
    const long nw = (long)gridDim.x * (blockDim.x >> 6);

    for (long m = (long)blockIdx.x * (blockDim.x >> 6) + wib; m < nrows; m += nw) {
        const int  half = (m >= E) ? 1 : 0;          // 0 = lr row, 1 = rl row
        const long e    = half ? (m - E) : m;
        const float* L = inL + e * 128;
        const float* R = inR + e * 128;

        // ---- layer 1: lane owns features f=lane and f=64+lane ----
        float a0 = 0.f, a1 = 0.f;
        for (int k = 0; k < 256; ++k) {
            // msg_lr[k] = (k<128)? left[k] : right[k-128]
            // msg_rl[k] = (k<128)? right[k] : left[k-128]
            float xk;
            if (!half) xk = (k < 128) ? L[k] : R[k - 128];
            else       xk = (k < 128) ? R[k] : L[k - 128];
            a0 += xk * W1[k * 128 + lane];
            a1 += xk * W1[k * 128 + 64 + lane];
        }
        const float h1a = fmaxf(a0 + b1[lane],      0.f);
        const float h1b = fmaxf(a1 + b1[64 + lane], 0.f);

        // ---- layer 2: h1[k] gathered by wave shuffle ----
        float c0 = 0.f, c1 = 0.f;
        for (int k = 0; k < 128; ++k) {
            const float hk = (k < 64) ? __shfl(h1a, k) : __shfl(h1b, k - 64);
            c0 += hk * W2[k * 128 + lane];
            c1 += hk * W2[k * 128 + 64 + lane];
        }
        const float h2a = fmaxf(c0 + b2[lane],      0.f);
        const float h2b = fmaxf(c1 + b2[64 + lane], 0.f);

        // ---- LayerNorm over the 128 features (wave reduce) ----
        float s1 = h2a + h2b;
        float s2 = h2a * h2a + h2b * h2b;
#pragma unroll
        for (int mm = 1; mm < 64; mm <<= 1) {
            s1 += __shfl_xor(s1, mm);
            s2 += __shfl_xor(s2, mm);
        }
        const float mu  = s1 * (1.f / 128.f);
        const float var = s2 * (1.f / 128.f) - mu * mu;
        const float rs  = rsqrtf(var + LN_EPS);

        out[m * 128 + lane]      = (h2a - mu) * rs * gamma[lane]      + beta[lane];
        out[m * 128 + 64 + lane] = (h2b - mu) * rs * gamma[64 + lane] + beta[64 + lane];
    }
}

extern "C" void kernel_launch(void* const* d_in, const int* in_sizes, int n_in,
                              void* d_out, int out_size, void* d_ws, size_t ws_size,
                              hipStream_t stream) {
    // Documented dict order (slot identities cross-validated by size/value/stats
    // in rounds 6/7): [in_right, in_left, W1, b1, W2, b2, gamma, beta]
    const float* inR   = (const float*)d_in[0];
    const float* inL   = (const float*)d_in[1];
    const float* W1    = (const float*)d_in[2];
    const float* b1    = (const float*)d_in[3];
    const float* W2    = (const float*)d_in[4];
    const float* b2    = (const float*)d_in[5];
    const float* gamma = (const float*)d_in[6];
    const float* beta  = (const float*)d_in[7];
    const int E = in_sizes[0] / 128;

    mpnn_naive<<<2048, 256, 0, stream>>>(inR, inL, W1, b1, W2, b2, gamma, beta,
                                         (float*)d_out, E);
}

// Round 12
// 223.772 us; speedup vs baseline: 39.3997x; 39.3997x over previous
//
#include <hip/hip_runtime.h>
#include <hip/hip_bf16.h>

#define LN_EPS 1e-5f

typedef __attribute__((ext_vector_type(8))) short bf16x8;
typedef __attribute__((ext_vector_type(4))) float f32x4;

__device__ __forceinline__ short f2bf(float x) {
    union { float f; unsigned u; } v; v.f = x;
    unsigned r = v.u + 0x7fff + ((v.u >> 16) & 1);   // RNE to bf16
    return (short)(r >> 16);
}

#define IN_STRIDE 528   // 512 data bytes + 16 pad (16B-aligned rows)
#define H_STRIDE  272   // 256 data bytes + 16 pad

// MFMA kernel (round-2 structure, validated interface: fp32 in, fp32 out).
// Block = 256 threads = 4 waves; wave w owns features [32w, 32w+32).
// Each iteration: 32 edges -> 64 output rows (32 lr + 32 rl).
// MFMA tuple (m92/m97-verified): A: lane(r=lane&15,q=lane>>4) elem i = A[m=r][k=8q+i]
//                                B: elem i = B[k=8q+i][n=r]
//                                D: lane(r,q) reg j = D[m=4q+j][n=r]
__global__ __launch_bounds__(256, 2) void mpnn_mfma(
    const float* __restrict__ inR, const float* __restrict__ inL,
    const float* __restrict__ W1, const float* __restrict__ b1,
    const float* __restrict__ W2, const float* __restrict__ b2,
    const float* __restrict__ gamma, const float* __restrict__ beta,
    float* __restrict__ out, int E, int niters)
{
    __shared__ __align__(16) char inA[32 * IN_STRIDE];  // [edge 0..31][k 0..255] bf16
    __shared__ __align__(16) char hbuf[64 * H_STRIDE];  // [erow 0..63][f 0..127] bf16
    __shared__ float2 lnp[4][4][16];                    // [wave][v][r] = (sum, sumsq)

    const int tid  = threadIdx.x;
    const int lane = tid & 63;
    const int wave = tid >> 6;
    const int r    = lane & 15;
    const int q    = lane >> 4;

    // ---- gather weight fragments from fp32 globals (L2-resident, once/block) ----
    bf16x8 A1[2][8], A2[2][4];
    float4 b1v[2], b2v[2], gv[2], bv[2];
#pragma unroll
    for (int t = 0; t < 2; ++t) {
        const int fr = wave * 32 + t * 16 + r;   // A-operand row feature
#pragma unroll
        for (int c = 0; c < 8; ++c)
#pragma unroll
            for (int i = 0; i < 8; ++i)
                A1[t][c][i] = f2bf(W1[(c * 32 + q * 8 + i) * 128 + fr]);
#pragma unroll
        for (int c = 0; c < 4; ++c)
#pragma unroll
            for (int i = 0; i < 8; ++i)
                A2[t][c][i] = f2bf(W2[(c * 32 + q * 8 + i) * 128 + fr]);
        const int fq = wave * 32 + t * 16 + q * 4; // D-row feature base for this lane
        b1v[t] = *(const float4*)(b1 + fq);
        b2v[t] = *(const float4*)(b2 + fq);
        gv[t]  = *(const float4*)(gamma + fq);
        bv[t]  = *(const float4*)(beta + fq);
    }

    for (int it = blockIdx.x; it < niters; it += gridDim.x) {
        const int e0 = it * 32;
        __syncthreads();   // prev iteration's inA/lnp readers done

        // ---- stage 32 edges x 256 k as bf16 (fp32 loads, short8 LDS writes) ----
#pragma unroll
        for (int j = 0; j < 4; ++j) {
            const int idx = j * 256 + tid;       // [0,1024) = [e 0..31][hw][c8 0..15]
            const int e  = idx >> 5;
            const int hw = (idx >> 4) & 1;       // 0: left half (k<128), 1: right half
            const int c8 = idx & 15;             // 8-float group within half-row
            int ee = e0 + e; if (ee >= E) ee = E - 1;
            const float* src = hw ? inR : inL;   // msg = left || right
            const float4 v0 = *(const float4*)(src + (long)ee * 128 + c8 * 8);
            const float4 v1 = *(const float4*)(src + (long)ee * 128 + c8 * 8 + 4);
            bf16x8 s;
            s[0] = f2bf(v0.x); s[1] = f2bf(v0.y); s[2] = f2bf(v0.z); s[3] = f2bf(v0.w);
            s[4] = f2bf(v1.x); s[5] = f2bf(v1.y); s[6] = f2bf(v1.z); s[7] = f2bf(v1.w);
            *(bf16x8*)(&inA[e * IN_STRIDE + hw * 256 + c8 * 16]) = s;
        }
        __syncthreads();   // inA ready

        // ---- layer 1: D[f][e]; lr pairs W1 chunk c with data chunk c,
        //      rl pairs W1 chunk (c+4)&7 with data chunk c ----
        f32x4 accL[2][2], accR[2][2];
#pragma unroll
        for (int t = 0; t < 2; ++t)
#pragma unroll
            for (int u = 0; u < 2; ++u) {
                accL[t][u] = f32x4{0.f, 0.f, 0.f, 0.f};
                accR[t][u] = f32x4{0.f, 0.f, 0.f, 0.f};
            }
#pragma unroll
        for (int c = 0; c < 8; ++c) {
            const bf16x8 x0 = *(const bf16x8*)(&inA[r        * IN_STRIDE + c * 64 + q * 16]);
            const bf16x8 x1 = *(const bf16x8*)(&inA[(16 + r) * IN_STRIDE + c * 64 + q * 16]);
            const int crl = (c + 4) & 7;
#pragma unroll
            for (int t = 0; t < 2; ++t) {
                accL[t][0] = __builtin_amdgcn_mfma_f32_16x16x32_bf16(A1[t][c],   x0, accL[t][0], 0, 0, 0);
                accL[t][1] = __builtin_amdgcn_mfma_f32_16x16x32_bf16(A1[t][c],   x1, accL[t][1], 0, 0, 0);
                accR[t][0] = __builtin_amdgcn_mfma_f32_16x16x32_bf16(A1[t][crl], x0, accR[t][0], 0, 0, 0);
                accR[t][1] = __builtin_amdgcn_mfma_f32_16x16x32_bf16(A1[t][crl], x1, accR[t][1], 0, 0, 0);
            }
        }

        // ---- h1 = relu(. + b1) -> hbuf; erow: [0,32)=lr, [32,64)=rl ----
#pragma unroll
        for (int t = 0; t < 2; ++t) {
            const int fb = wave * 32 + t * 16 + q * 4;   // features of regs j=0..3
#pragma unroll
            for (int v = 0; v < 4; ++v) {                // v = 2*is_rl + edge_tile
                const f32x4 a = (v < 2) ? accL[t][v] : accR[t][v - 2];
                short4 s;
                s.x = f2bf(fmaxf(a[0] + b1v[t].x, 0.f));
                s.y = f2bf(fmaxf(a[1] + b1v[t].y, 0.f));
                s.z = f2bf(fmaxf(a[2] + b1v[t].z, 0.f));
                s.w = f2bf(fmaxf(a[3] + b1v[t].w, 0.f));
                *(short4*)(&hbuf[(v * 16 + r) * H_STRIDE + fb * 2]) = s;
            }
        }
        __syncthreads();   // hbuf ready

        // ---- layer 2: D[f][e] over 4 groups of 16 rows ----
        f32x4 acc2[2][4];
#pragma unroll
        for (int t = 0; t < 2; ++t)
#pragma unroll
            for (int v = 0; v < 4; ++v) acc2[t][v] = f32x4{0.f, 0.f, 0.f, 0.f};
#pragma unroll
        for (int c = 0; c < 4; ++c) {
#pragma unroll
            for (int v = 0; v < 4; ++v) {
                const bf16x8 y = *(const bf16x8*)(&hbuf[(v * 16 + r) * H_STRIDE + c * 64 + q * 16]);
#pragma unroll
                for (int t = 0; t < 2; ++t)
                    acc2[t][v] = __builtin_amdgcn_mfma_f32_16x16x32_bf16(A2[t][c], y, acc2[t][v], 0, 0, 0);
            }
        }

        // ---- bias + relu + LN partials (per edge = (v, r)) ----
        float s1[4] = {0.f, 0.f, 0.f, 0.f}, s2[4] = {0.f, 0.f, 0.f, 0.f};
#pragma unroll
        for (int t = 0; t < 2; ++t)
#pragma unroll
            for (int v = 0; v < 4; ++v) {
                f32x4 a = acc2[t][v];
                a[0] = fmaxf(a[0] + b2v[t].x, 0.f);
                a[1] = fmaxf(a[1] + b2v[t].y, 0.f);
                a[2] = fmaxf(a[2] + b2v[t].z, 0.f);
                a[3] = fmaxf(a[3] + b2v[t].w, 0.f);
                acc2[t][v] = a;
                s1[v] += a[0] + a[1] + a[2] + a[3];
                s2[v] += a[0] * a[0] + a[1] * a[1] + a[2] * a[2] + a[3] * a[3];
            }
#pragma unroll
        for (int v = 0; v < 4; ++v) {
            s1[v] += __shfl_xor(s1[v], 16);
            s1[v] += __shfl_xor(s1[v], 32);
            s2[v] += __shfl_xor(s2[v], 16);
            s2[v] += __shfl_xor(s2[v], 32);
        }
        if (lane < 16) {
#pragma unroll
            for (int v = 0; v < 4; ++v)
                lnp[wave][v][lane] = make_float2(s1[v], s2[v]);
        }
        __syncthreads();   // partials ready

        // ---- finalize LN + fp32 store ----
#pragma unroll
        for (int v = 0; v < 4; ++v) {
            float S1 = 0.f, S2 = 0.f;
#pragma unroll
            for (int w = 0; w < 4; ++w) {
                const float2 p = lnp[w][v][r];
                S1 += p.x; S2 += p.y;
            }
            const float mu  = S1 * (1.f / 128.f);
            const float var = S2 * (1.f / 128.f) - mu * mu;
            const float rs  = rsqrtf(var + LN_EPS);
            const int el = (v & 1) * 16 + r;            // edge within this iteration
            const bool ok = (e0 + el) < E;
            const long orow = ((v < 2) ? 0L : (long)E) + e0 + el;
#pragma unroll
            for (int t = 0; t < 2; ++t) {
                const int fb = wave * 32 + t * 16 + q * 4;
                const f32x4 a = acc2[t][v];
                float4 o;
                o.x = (a[0] - mu) * rs * gv[t].x + bv[t].x;
                o.y = (a[1] - mu) * rs * gv[t].y + bv[t].y;
                o.z = (a[2] - mu) * rs * gv[t].z + bv[t].z;
                o.w = (a[3] - mu) * rs * gv[t].w + bv[t].w;
                if (ok)
                    *(float4*)(out + orow * 128 + fb) = o;
            }
        }
    }
}

extern "C" void kernel_launch(void* const* d_in, const int* in_sizes, int n_in,
                              void* d_out, int out_size, void* d_ws, size_t ws_size,
                              hipStream_t stream) {
    // Validated interface (round 11): dict order, fp32 inputs, fp32 output.
    const float* inR   = (const float*)d_in[0];
    const float* inL   = (const float*)d_in[1];
    const float* W1    = (const float*)d_in[2];
    const float* b1    = (const float*)d_in[3];
    const float* W2    = (const float*)d_in[4];
    const float* b2    = (const float*)d_in[5];
    const float* gamma = (const float*)d_in[6];
    const float* beta  = (const float*)d_in[7];
    const int E = in_sizes[0] / 128;

    const int niters = (E + 31) / 32;
    const int grid = niters < 2048 ? niters : 2048;
    mpnn_mfma<<<grid, 256, 0, stream>>>(inR, inL, W1, b1, W2, b2, gamma, beta,
                                        (float*)d_out, E, niters);
}